// Round 1
// baseline (619.980 us; speedup 1.0000x reference)
//
#include <hip/hip_runtime.h>
#include <stdint.h>

#define DEV __device__ __forceinline__

using f32x4 = __attribute__((ext_vector_type(4))) float;
using s16x8 = __attribute__((ext_vector_type(8))) short;

DEV uint16_t f2bf(float f) {
  union { float f; uint32_t u; } v; v.f = f;
  uint32_t r = v.u + 0x7fffu + ((v.u >> 16) & 1u);  // round-to-nearest-even
  return (uint16_t)(r >> 16);
}
DEV uint32_t pack2(float a, float b) {
  return (uint32_t)f2bf(a) | ((uint32_t)f2bf(b) << 16);
}

// async global->LDS, 16B per lane; LDS dest = wave-uniform base + lane*16
DEV void gload_lds16(const void* g, void* l) {
  __builtin_amdgcn_global_load_lds(
      (__attribute__((address_space(1))) void*)(void*)g,
      (__attribute__((address_space(3))) void*)l, 16, 0, 0);
}

// ---------------------------------------------------------------------------
// f32 -> bf16 weights conversion, all 4 weights in one launch.
// ---------------------------------------------------------------------------
__global__ __launch_bounds__(256) void cvt_w_kernel(const float* __restrict__ Wq,
                                                    const float* __restrict__ Wk,
                                                    const float* __restrict__ Wv,
                                                    const float* __restrict__ Wp,
                                                    uint16_t* __restrict__ wqb,
                                                    uint16_t* __restrict__ wkb,
                                                    uint16_t* __restrict__ wvb,
                                                    uint16_t* __restrict__ wpb) {
  const int idx = blockIdx.x * blockDim.x + threadIdx.x;  // 4*131072 total
  const int region = idx >> 17;
  const int i = idx & 131071;
  const float* src = region == 0 ? Wq : region == 1 ? Wk : region == 2 ? Wv : Wp;
  uint16_t* dst = region == 0 ? wqb : region == 1 ? wkb : region == 2 ? wvb : wpb;
  const float4* s = (const float4*)src;
  float4 a = s[2 * i];
  float4 b = s[2 * i + 1];
  uint4 pk;
  pk.x = pack2(a.x, a.y);
  pk.y = pack2(a.z, a.w);
  pk.z = pack2(b.x, b.y);
  pk.w = pack2(b.z, b.w);
  ((uint4*)dst)[i] = pk;
}

// ---------------------------------------------------------------------------
// NT GEMM: C[m][n] = sum_k A[m][k] * B[n][k]  (+bias), bf16 MFMA 16x16x32
// Tile 128x128, BK=32, 256 threads = 4 waves, each wave 64x64 (4x4 subtiles).
// 1-D grid + XCD-stripe swizzle (see decode below).
// LDS 16B-chunk XOR swizzle pc = lc ^ ((m>>1)&3): <=2-way aliasing (free).
//
// R1 change: 2-phase double-buffered pipeline (T3-minimum). Previous version
// issued global_load_lds for the CURRENT tile and immediately drained it at
// __syncthreads (vmcnt(0) with zero compute in between -> full load latency
// exposed every K-step; MfmaUtil 17%). Now: prefetch tile t+1 into buf^1
// BEFORE the ds_read+MFMA of tile t, so the implicit vmcnt(0) in the single
// per-iteration __syncthreads lands after a full compute phase has covered
// the latency. One barrier per K-step instead of two.
// ---------------------------------------------------------------------------
struct GemmBatch {
  const void* A[3];
  const uint16_t* B[3];
  void* C[3];
};

template <bool A_F32, bool OUT_BF16>
__global__ __launch_bounds__(256) void gemm_bt(GemmBatch gb,
                                               const float* __restrict__ bias,
                                               int M, int N, int K) {
  constexpr int BM = 128, BN = 128, BK = 32;
  __shared__ __align__(16) uint16_t Alds[2][BM * BK];
  __shared__ __align__(16) uint16_t Blds[2][BN * BK];

  // XCD-stripe decode: w = xcd + 8*(bn + nbn*(bml + bmpx*z))
  const int w = blockIdx.x;
  const int xcd = w & 7;
  int local = w >> 3;
  const int nbn = N >> 7;
  const int bmpx = (M >> 7) >> 3;
  const int bn = local % nbn;
  local /= nbn;
  const int bml = local % bmpx;
  const int z = local / bmpx;
  const int bm0 = (xcd * bmpx + bml) * BM;
  const int bn0 = bn * BN;

  const void* __restrict__ Ap = gb.A[z];
  const uint16_t* __restrict__ Bp = gb.B[z];
  void* __restrict__ Cp = gb.C[z];

  const int tid = threadIdx.x;
  const int wave = tid >> 6;
  const int lane = tid & 63;
  const int quad = lane >> 4;
  const int l16 = lane & 15;
  const int wm = (wave >> 1) * 64;
  const int wn = (wave & 1) * 64;

  f32x4 acc[4][4];
#pragma unroll
  for (int i = 0; i < 4; ++i)
#pragma unroll
    for (int j = 0; j < 4; ++j) acc[i][j] = (f32x4){0.f, 0.f, 0.f, 0.f};

  // B tile async staging: chunk p = wave*128 + j*64 + lane lands at LDS byte p*16
  const uint16_t* bsrc[2];
  int bofs[2];  // uint16 index within one buffer
#pragma unroll
  for (int j = 0; j < 2; ++j) {
    const int p = wave * 128 + j * 64 + lane;
    const int m = p >> 2;
    const int lc = (p & 3) ^ ((m >> 1) & 3);
    bsrc[j] = Bp + (size_t)(bn0 + m) * K + lc * 8;
    bofs[j] = (wave * 128 + j * 64) * 8;  // wave-uniform base
  }

  const float* asrcf[2];
  int adst_f[2];
  const uint16_t* asrc16[2];
  int aofs16[2];
  float4 areg[2][2];  // f32 register staging for the NEXT tile (A_F32 path)
  if constexpr (A_F32) {
    // register staging with cvt: thread handles chunks tid and tid+256
#pragma unroll
    for (int c = 0; c < 2; ++c) {
      const int p = tid + c * 256;
      const int m = p >> 2;
      const int lc = (p & 3) ^ ((m >> 1) & 3);
      asrcf[c] = (const float*)Ap + (size_t)(bm0 + m) * K + lc * 8;
      adst_f[c] = p * 8;  // ushort index within one buffer; byte p*16
    }
    // prologue: load tile-0 A f32 into regs
#pragma unroll
    for (int c = 0; c < 2; ++c) {
      const float4* g = (const float4*)asrcf[c];
      areg[c][0] = g[0];
      areg[c][1] = g[1];
    }
  } else {
#pragma unroll
    for (int j = 0; j < 2; ++j) {
      const int p = wave * 128 + j * 64 + lane;
      const int m = p >> 2;
      const int lc = (p & 3) ^ ((m >> 1) & 3);
      asrc16[j] = (const uint16_t*)Ap + (size_t)(bm0 + m) * K + lc * 8;
      aofs16[j] = (wave * 128 + j * 64) * 8;
    }
  }

  // ---- prologue: stage tile 0 into buffer 0 ----
#pragma unroll
  for (int j = 0; j < 2; ++j) gload_lds16(bsrc[j], &Blds[0][bofs[j]]);
  if constexpr (!A_F32) {
#pragma unroll
    for (int j = 0; j < 2; ++j) gload_lds16(asrc16[j], &Alds[0][aofs16[j]]);
  } else {
#pragma unroll
    for (int c = 0; c < 2; ++c) {
      uint4 pk;
      pk.x = pack2(areg[c][0].x, areg[c][0].y);
      pk.y = pack2(areg[c][0].z, areg[c][0].w);
      pk.z = pack2(areg[c][1].x, areg[c][1].y);
      pk.w = pack2(areg[c][1].z, areg[c][1].w);
      *(uint4*)&Alds[0][adst_f[c]] = pk;
    }
  }
  __syncthreads();  // drains prologue staging (vmcnt+lgkm) for all waves

  int buf = 0;
  for (int k0 = 0; k0 < K; k0 += BK) {
    const bool hn = (k0 + BK < K);  // block-uniform
    const int nb = buf ^ 1;

    // ---- issue NEXT tile's staging first; it stays in flight through the
    // ds_read+MFMA phase below and is drained by the end-of-iter barrier ----
    if (hn) {
#pragma unroll
      for (int j = 0; j < 2; ++j) gload_lds16(bsrc[j] + k0 + BK, &Blds[nb][bofs[j]]);
      if constexpr (A_F32) {
#pragma unroll
        for (int c = 0; c < 2; ++c) {
          const float4* g = (const float4*)(asrcf[c] + k0 + BK);
          areg[c][0] = g[0];
          areg[c][1] = g[1];
        }
      } else {
#pragma unroll
        for (int j = 0; j < 2; ++j)
          gload_lds16(asrc16[j] + k0 + BK, &Alds[nb][aofs16[j]]);
      }
    }

    // ---- compute current tile from buf ----
    s16x8 af[4], bfv[4];
#pragma unroll
    for (int s = 0; s < 4; ++s) {
      const int ml = wm + s * 16 + l16;
      const int ca = ml * 4 + (quad ^ ((ml >> 1) & 3));
      af[s] = *(const s16x8*)&Alds[buf][ca * 8];
      const int nl = wn + s * 16 + l16;
      const int cb = nl * 4 + (quad ^ ((nl >> 1) & 3));
      bfv[s] = *(const s16x8*)&Blds[buf][cb * 8];
    }
#pragma unroll
    for (int sm = 0; sm < 4; ++sm)
#pragma unroll
      for (int sn = 0; sn < 4; ++sn)
        acc[sm][sn] =
            __builtin_amdgcn_mfma_f32_16x16x32_bf16(af[sm], bfv[sn], acc[sm][sn], 0, 0, 0);

    if (hn) {
      if constexpr (A_F32) {
        // pack the prefetched f32 regs into the next buffer; the vmcnt wait
        // for areg sits here, after the MFMA phase covered the load latency
#pragma unroll
        for (int c = 0; c < 2; ++c) {
          uint4 pk;
          pk.x = pack2(areg[c][0].x, areg[c][0].y);
          pk.y = pack2(areg[c][0].z, areg[c][0].w);
          pk.z = pack2(areg[c][1].x, areg[c][1].y);
          pk.w = pack2(areg[c][1].z, areg[c][1].w);
          *(uint4*)&Alds[nb][adst_f[c]] = pk;
        }
      }
      __syncthreads();  // single barrier per K-step: drains next-tile staging
      buf = nb;
    }
  }

  // epilogue: C/D layout col = lane&15, row = quad*4 + r (m89-verified)
#pragma unroll
  for (int sm = 0; sm < 4; ++sm) {
    const int mrow = bm0 + wm + sm * 16 + quad * 4;
#pragma unroll
    for (int sn = 0; sn < 4; ++sn) {
      const int ncol = bn0 + wn + sn * 16 + l16;
      if constexpr (OUT_BF16) {
        uint16_t* Cb = (uint16_t*)Cp;
#pragma unroll
        for (int r = 0; r < 4; ++r) Cb[(size_t)(mrow + r) * N + ncol] = f2bf(acc[sm][sn][r]);
      } else {
        float* Cf = (float*)Cp;
        const float bv = bias[ncol];
#pragma unroll
        for (int r = 0; r < 4; ++r) Cf[(size_t)(mrow + r) * N + ncol] = acc[sm][sn][r] + bv;
      }
    }
  }
}

// ---------------------------------------------------------------------------
// MFMA attention: one WAVE per token. S = Q·K^T via 2x mfma_16x16x32_bf16;
// softmax over g via shfl_xor within 16-lane groups; P through 512B LDS to
// A-layout; V staged coalesced into an XOR-swizzled LDS tile (chunk cc of row
// g stored at cc ^ (2*(g>>3)) so the column-wise B-frag reads are
// bank-conflict-free); PV = 4x zero-padded mfma_16x16x32.
// Store into "buggy reshape" position X2[b, h*128 + n/16, (n%16)*64 + d].
// ---------------------------------------------------------------------------
__global__ __launch_bounds__(256) void attn_kernel(const uint16_t* __restrict__ qb,
                                                   const uint16_t* __restrict__ kb,
                                                   const uint16_t* __restrict__ vb,
                                                   uint16_t* __restrict__ x2b) {
  __shared__ __align__(16) uint16_t plds[4][16 * 16];  // per-wave P (16x16 bf16)
  __shared__ __align__(16) uint16_t vlds[4][16 * 64];  // per-wave V tile, swizzled

  const int tid = threadIdx.x;
  const int wave = tid >> 6;
  const int lane = tid & 63;
  const int quad = lane >> 4;
  const int l16 = lane & 15;
  const int token = blockIdx.x * 4 + wave;
  const int b = token >> 11;
  const int n = token & 2047;
  const size_t base = (size_t)token * 1024;

  // --- stage V (coalesced 16B chunks, XOR-swizzled columns) ---
  {
    const uint16_t* vt = vb + base;  // 16x64 bf16, contiguous
    uint16_t* vl = vlds[wave];
#pragma unroll
    for (int c2 = 0; c2 < 2; ++c2) {
      const int p = lane + c2 * 64;  // chunk index; src = 16B at p*16
      const int g = p >> 3;
      const int cc = p & 7;
      const int cs = cc ^ (2 * (g >> 3));
      *(uint4*)&vl[g * 64 + cs * 8] = *(const uint4*)&vt[p * 8];
    }
  }

  // --- S = Q K^T (16x16, K=64) ---
  const uint16_t* qrow = qb + base + l16 * 64 + quad * 8;
  const uint16_t* krow = kb + base + l16 * 64 + quad * 8;
  s16x8 aq0 = *(const s16x8*)qrow;
  s16x8 aq1 = *(const s16x8*)(qrow + 32);
  s16x8 bk0 = *(const s16x8*)krow;
  s16x8 bk1 = *(const s16x8*)(krow + 32);
  f32x4 s = (f32x4){0.f, 0.f, 0.f, 0.f};
  s = __builtin_amdgcn_mfma_f32_16x16x32_bf16(aq0, bk0, s, 0, 0, 0);
  s = __builtin_amdgcn_mfma_f32_16x16x32_bf16(aq1, bk1, s, 0, 0, 0);
  // lane holds S[h=quad*4+r][g=l16], r=0..3

  // --- softmax over g (across the 16 lanes sharing quad) ---
  float p[4];
#pragma unroll
  for (int r = 0; r < 4; ++r) {
    float v = s[r] * 0.125f;  // SCALE = 64^-0.5
    float mx = v;
#pragma unroll
    for (int off = 1; off < 16; off <<= 1) mx = fmaxf(mx, __shfl_xor(mx, off));
    float e = __expf(v - mx);
    float sum = e;
#pragma unroll
    for (int off = 1; off < 16; off <<= 1) sum += __shfl_xor(sum, off);
    p[r] = e / sum;
  }

  // --- transpose P to A-layout via LDS ---
  uint16_t* pb = plds[wave];
#pragma unroll
  for (int r = 0; r < 4; ++r) pb[(quad * 4 + r) * 16 + l16] = f2bf(p[r]);
  __syncthreads();
  s16x8 ap = (s16x8){0, 0, 0, 0, 0, 0, 0, 0};
  if (quad < 2) ap = *(const s16x8*)&pb[l16 * 16 + quad * 8];  // P[l16][quad*8+j]

  // --- V B-frags from LDS: bv[c][j] = V[g=quad*8+j][d=c*16+l16] ---
  s16x8 bv[4];
#pragma unroll
  for (int c = 0; c < 4; ++c) bv[c] = (s16x8){0, 0, 0, 0, 0, 0, 0, 0};
  if (quad < 2) {
    const uint16_t* vl = vlds[wave];
#pragma unroll
    for (int c = 0; c < 4; ++c) {
      const int cc = c * 2 + (l16 >> 3);
      const int dlo = l16 & 7;
#pragma unroll
      for (int j = 0; j < 8; ++j) {
        const int g = quad * 8 + j;
        const int cs = cc ^ (2 * (g >> 3));
        bv[c][j] = (short)vl[g * 64 + cs * 8 + dlo];
      }
    }
  }

  // --- X = P V (16x64) ---
  f32x4 xacc[4];
#pragma unroll
  for (int c = 0; c < 4; ++c) {
    xacc[c] = (f32x4){0.f, 0.f, 0.f, 0.f};
    xacc[c] = __builtin_amdgcn_mfma_f32_16x16x32_bf16(ap, bv[c], xacc[c], 0, 0, 0);
  }

  // --- store: lane has x[h=quad*4+r][d=c*16+l16] ---
  uint16_t* xout =
      x2b + (size_t)b * (2048 * 1024) + (size_t)(n & 15) * 64 + (size_t)(n >> 4) * 1024;
#pragma unroll
  for (int c = 0; c < 4; ++c) {
    const int d = c * 16 + l16;
#pragma unroll
    for (int r = 0; r < 4; ++r) {
      const int h = quad * 4 + r;
      xout[(size_t)h * 128 * 1024 + d] = f2bf(xacc[c][r]);
    }
  }
}

// ---------------------------------------------------------------------------
extern "C" void kernel_launch(void* const* d_in, const int* in_sizes, int n_in,
                              void* d_out, int out_size, void* d_ws, size_t ws_size,
                              hipStream_t stream) {
  const float* query = (const float*)d_in[0];
  const float* key = (const float*)d_in[1];
  const float* value = (const float*)d_in[2];
  // d_in[3]=xpos, d_in[4]=ypos unused (rope is None)
  const float* Wq = (const float*)d_in[5];
  const float* Wk = (const float*)d_in[6];
  const float* Wv = (const float*)d_in[7];
  const float* Wp = (const float*)d_in[8];
  const float* bp = (const float*)d_in[9];
  float* out = (float*)d_out;

  const int C = 1024;
  const int M = 8 * 2048;  // 16384 tokens
  const size_t MC = (size_t)M * C;

  // workspace layout (bf16 = uint16): q,k,v,x2 (4*32 MiB) + 4 weights (8 MiB) = 136 MiB
  uint16_t* ws = (uint16_t*)d_ws;
  uint16_t* qb = ws;
  uint16_t* kb = qb + MC;
  uint16_t* vb = kb + MC;
  uint16_t* x2b = vb + MC;
  uint16_t* wqb = x2b + MC;
  uint16_t* wkb = wqb + (size_t)C * C;
  uint16_t* wvb = wkb + (size_t)C * C;
  uint16_t* wpb = wvb + (size_t)C * C;

  // all 4 weight conversions in one launch
  cvt_w_kernel<<<dim3(4 * 131072 / 256), dim3(256), 0, stream>>>(Wq, Wk, Wv, Wp, wqb, wkb,
                                                                 wvb, wpb);

  // batched QKV projections; 1-D grid, XCD-stripe swizzle decoded in-kernel
  GemmBatch qkv;
  qkv.A[0] = query;  qkv.B[0] = wqb;  qkv.C[0] = qb;
  qkv.A[1] = key;    qkv.B[1] = wkb;  qkv.C[1] = kb;
  qkv.A[2] = value;  qkv.B[2] = wvb;  qkv.C[2] = vb;
  gemm_bt<true, true><<<dim3((M / 128) * (C / 128) * 3), dim3(256), 0, stream>>>(
      qkv, nullptr, M, C, C);

  attn_kernel<<<dim3(M / 4), dim3(256), 0, stream>>>(qb, kb, vb, x2b);

  GemmBatch fin;
  fin.A[0] = x2b;  fin.B[0] = wpb;  fin.C[0] = out;
  fin.A[1] = x2b;  fin.B[1] = wpb;  fin.C[1] = out;
  fin.A[2] = x2b;  fin.B[2] = wpb;  fin.C[2] = out;
  gemm_bt<false, false><<<dim3((M / 128) * (C / 128)), dim3(256), 0, stream>>>(fin, bp, M,
                                                                               C, C);
}

// Round 2
// 448.281 us; speedup vs baseline: 1.3830x; 1.3830x over previous
//
#include <hip/hip_runtime.h>
#include <stdint.h>

#define DEV __device__ __forceinline__

using f32x4 = __attribute__((ext_vector_type(4))) float;
using s16x8 = __attribute__((ext_vector_type(8))) short;

DEV uint16_t f2bf(float f) {
  union { float f; uint32_t u; } v; v.f = f;
  uint32_t r = v.u + 0x7fffu + ((v.u >> 16) & 1u);  // round-to-nearest-even
  return (uint16_t)(r >> 16);
}
DEV uint32_t pack2(float a, float b) {
  return (uint32_t)f2bf(a) | ((uint32_t)f2bf(b) << 16);
}

// async global->LDS, 16B per lane; LDS dest = wave-uniform base + lane*16
DEV void gload_lds16(const void* g, void* l) {
  __builtin_amdgcn_global_load_lds(
      (__attribute__((address_space(1))) void*)(void*)g,
      (__attribute__((address_space(3))) void*)l, 16, 0, 0);
}

// ---------------------------------------------------------------------------
// f32 -> bf16 conversion for q/k/v inputs (3 x 16M elems) AND the 4 weight
// matrices (4 x 1M elems), one launch. Each thread converts 8 elems (32B
// read, 16B write, fully coalesced).
// R2: inputs are now converted up front so ALL GEMMs use the pure bf16
// global_load_lds staging path (reg-staged f32 A measured 412 TF vs the
// guide's 874 TF for gload_lds staging at the same structure).
// ---------------------------------------------------------------------------
__global__ __launch_bounds__(256) void cvt_all_kernel(
    const float* __restrict__ q, const float* __restrict__ k,
    const float* __restrict__ v, const float* __restrict__ Wq,
    const float* __restrict__ Wk, const float* __restrict__ Wv,
    const float* __restrict__ Wp, uint16_t* __restrict__ qc,
    uint16_t* __restrict__ kc, uint16_t* __restrict__ vc,
    uint16_t* __restrict__ wqb, uint16_t* __restrict__ wkb,
    uint16_t* __restrict__ wvb, uint16_t* __restrict__ wpb) {
  const int idx = blockIdx.x * blockDim.x + threadIdx.x;
  const float* src;
  uint16_t* dst;
  int i;
  if (idx < 3 * 2097152) {  // inputs: 16M f32 each -> 2M threads each
    const int t = idx >> 21;
    i = idx & 2097151;
    src = t == 0 ? q : t == 1 ? k : v;
    dst = t == 0 ? qc : t == 1 ? kc : vc;
  } else {  // weights: 1M f32 each -> 128K threads each
    const int j = idx - 3 * 2097152;
    const int r = j >> 17;
    i = j & 131071;
    src = r == 0 ? Wq : r == 1 ? Wk : r == 2 ? Wv : Wp;
    dst = r == 0 ? wqb : r == 1 ? wkb : r == 2 ? wvb : wpb;
  }
  const float4* s = (const float4*)src;
  float4 a = s[2 * i];
  float4 b = s[2 * i + 1];
  uint4 pk;
  pk.x = pack2(a.x, a.y);
  pk.y = pack2(a.z, a.w);
  pk.z = pack2(b.x, b.y);
  pk.w = pack2(b.z, b.w);
  ((uint4*)dst)[i] = pk;
}

// ---------------------------------------------------------------------------
// NT GEMM: C[m][n] = sum_k A[m][k] * B[n][k]  (+bias), bf16 MFMA 16x16x32
// Tile 128x128, BK=32, 256 threads = 4 waves, each wave 64x64 (4x4 subtiles).
// 1-D grid + XCD-stripe swizzle: hardware maps workgroup w -> XCD (w % 8);
// XCD x gets the contiguous bm stripe [x*bmpx, (x+1)*bmpx), bn iterates
// fastest so the 8 bn-sharers of one A row-tile hit the same XCD's L2.
// LDS 16B-chunk XOR swizzle pc = lc ^ ((m>>1)&3): <=2-way aliasing (free).
// Structure = round-0 (m97-style): single LDS buffer, issue 4 gload_lds,
// barrier, ds_read+MFMA, barrier. R1's explicit double-buffer REGRESSED
// (occupancy 31.6->22.4%): latency hiding here is cross-block (m114), and
// 2x LDS + 2x pointer state traded that away. Do not re-introduce dbuf at
// this tile size.
// ---------------------------------------------------------------------------
struct GemmBatch {
  const uint16_t* A[3];
  const uint16_t* B[3];
  void* C[3];
};

template <bool OUT_BF16>
__global__ __launch_bounds__(256) void gemm_bt(GemmBatch gb,
                                               const float* __restrict__ bias,
                                               int M, int N, int K) {
  constexpr int BM = 128, BN = 128, BK = 32;
  __shared__ __align__(16) uint16_t Alds[BM * BK];
  __shared__ __align__(16) uint16_t Blds[BN * BK];

  // XCD-stripe decode: w = xcd + 8*(bn + nbn*(bml + bmpx*z))
  const int w = blockIdx.x;
  const int xcd = w & 7;
  int local = w >> 3;
  const int nbn = N >> 7;
  const int bmpx = (M >> 7) >> 3;
  const int bn = local % nbn;
  local /= nbn;
  const int bml = local % bmpx;
  const int z = local / bmpx;
  const int bm0 = (xcd * bmpx + bml) * BM;
  const int bn0 = bn * BN;

  const uint16_t* __restrict__ Ap = gb.A[z];
  const uint16_t* __restrict__ Bp = gb.B[z];
  void* __restrict__ Cp = gb.C[z];

  const int tid = threadIdx.x;
  const int wave = tid >> 6;
  const int lane = tid & 63;
  const int quad = lane >> 4;
  const int l16 = lane & 15;
  const int wm = (wave >> 1) * 64;
  const int wn = (wave & 1) * 64;

  f32x4 acc[4][4];
#pragma unroll
  for (int i = 0; i < 4; ++i)
#pragma unroll
    for (int j = 0; j < 4; ++j) acc[i][j] = (f32x4){0.f, 0.f, 0.f, 0.f};

  // async staging: chunk p = wave*128 + j*64 + lane lands at LDS byte p*16
  const uint16_t* asrc[2];
  const uint16_t* bsrc[2];
  uint16_t* adst[2];
  uint16_t* bdst[2];
#pragma unroll
  for (int j = 0; j < 2; ++j) {
    const int p = wave * 128 + j * 64 + lane;
    const int m = p >> 2;
    const int lc = (p & 3) ^ ((m >> 1) & 3);
    asrc[j] = Ap + (size_t)(bm0 + m) * K + lc * 8;
    bsrc[j] = Bp + (size_t)(bn0 + m) * K + lc * 8;
    adst[j] = &Alds[(wave * 128 + j * 64) * 8];  // wave-uniform base
    bdst[j] = &Blds[(wave * 128 + j * 64) * 8];
  }

  for (int k0 = 0; k0 < K; k0 += BK) {
#pragma unroll
    for (int j = 0; j < 2; ++j) gload_lds16(bsrc[j] + k0, bdst[j]);
#pragma unroll
    for (int j = 0; j < 2; ++j) gload_lds16(asrc[j] + k0, adst[j]);
    __syncthreads();

    s16x8 af[4], bfv[4];
#pragma unroll
    for (int s = 0; s < 4; ++s) {
      const int ml = wm + s * 16 + l16;
      const int ca = ml * 4 + (quad ^ ((ml >> 1) & 3));
      af[s] = *(const s16x8*)&Alds[ca * 8];
      const int nl = wn + s * 16 + l16;
      const int cb = nl * 4 + (quad ^ ((nl >> 1) & 3));
      bfv[s] = *(const s16x8*)&Blds[cb * 8];
    }
#pragma unroll
    for (int sm = 0; sm < 4; ++sm)
#pragma unroll
      for (int sn = 0; sn < 4; ++sn)
        acc[sm][sn] =
            __builtin_amdgcn_mfma_f32_16x16x32_bf16(af[sm], bfv[sn], acc[sm][sn], 0, 0, 0);
    __syncthreads();
  }

  // epilogue: C/D layout col = lane&15, row = quad*4 + r (m89-verified)
#pragma unroll
  for (int sm = 0; sm < 4; ++sm) {
    const int mrow = bm0 + wm + sm * 16 + quad * 4;
#pragma unroll
    for (int sn = 0; sn < 4; ++sn) {
      const int ncol = bn0 + wn + sn * 16 + l16;
      if constexpr (OUT_BF16) {
        uint16_t* Cb = (uint16_t*)Cp;
#pragma unroll
        for (int r = 0; r < 4; ++r) Cb[(size_t)(mrow + r) * N + ncol] = f2bf(acc[sm][sn][r]);
      } else {
        float* Cf = (float*)Cp;
        const float bv = bias[ncol];
#pragma unroll
        for (int r = 0; r < 4; ++r) Cf[(size_t)(mrow + r) * N + ncol] = acc[sm][sn][r] + bv;
      }
    }
  }
}

// ---------------------------------------------------------------------------
// MFMA attention: one WAVE per token. S = Q·K^T via 2x mfma_16x16x32_bf16;
// softmax over g via shfl_xor within 16-lane groups; P through 512B LDS to
// A-layout; V staged coalesced into an XOR-swizzled LDS tile (chunk cc of row
// g stored at cc ^ (2*(g>>3)) so the column-wise B-frag reads are
// bank-conflict-free); PV = 4x zero-padded mfma_16x16x32.
// Store into "buggy reshape" position X2[b, h*128 + n/16, (n%16)*64 + d].
// ---------------------------------------------------------------------------
__global__ __launch_bounds__(256) void attn_kernel(const uint16_t* __restrict__ qb,
                                                   const uint16_t* __restrict__ kb,
                                                   const uint16_t* __restrict__ vb,
                                                   uint16_t* __restrict__ x2b) {
  __shared__ __align__(16) uint16_t plds[4][16 * 16];  // per-wave P (16x16 bf16)
  __shared__ __align__(16) uint16_t vlds[4][16 * 64];  // per-wave V tile, swizzled

  const int tid = threadIdx.x;
  const int wave = tid >> 6;
  const int lane = tid & 63;
  const int quad = lane >> 4;
  const int l16 = lane & 15;
  const int token = blockIdx.x * 4 + wave;
  const int b = token >> 11;
  const int n = token & 2047;
  const size_t base = (size_t)token * 1024;

  // --- stage V (coalesced 16B chunks, XOR-swizzled columns) ---
  {
    const uint16_t* vt = vb + base;  // 16x64 bf16, contiguous
    uint16_t* vl = vlds[wave];
#pragma unroll
    for (int c2 = 0; c2 < 2; ++c2) {
      const int p = lane + c2 * 64;  // chunk index; src = 16B at p*16
      const int g = p >> 3;
      const int cc = p & 7;
      const int cs = cc ^ (2 * (g >> 3));
      *(uint4*)&vl[g * 64 + cs * 8] = *(const uint4*)&vt[p * 8];
    }
  }

  // --- S = Q K^T (16x16, K=64) ---
  const uint16_t* qrow = qb + base + l16 * 64 + quad * 8;
  const uint16_t* krow = kb + base + l16 * 64 + quad * 8;
  s16x8 aq0 = *(const s16x8*)qrow;
  s16x8 aq1 = *(const s16x8*)(qrow + 32);
  s16x8 bk0 = *(const s16x8*)krow;
  s16x8 bk1 = *(const s16x8*)(krow + 32);
  f32x4 s = (f32x4){0.f, 0.f, 0.f, 0.f};
  s = __builtin_amdgcn_mfma_f32_16x16x32_bf16(aq0, bk0, s, 0, 0, 0);
  s = __builtin_amdgcn_mfma_f32_16x16x32_bf16(aq1, bk1, s, 0, 0, 0);
  // lane holds S[h=quad*4+r][g=l16], r=0..3

  // --- softmax over g (across the 16 lanes sharing quad) ---
  float p[4];
#pragma unroll
  for (int r = 0; r < 4; ++r) {
    float v = s[r] * 0.125f;  // SCALE = 64^-0.5
    float mx = v;
#pragma unroll
    for (int off = 1; off < 16; off <<= 1) mx = fmaxf(mx, __shfl_xor(mx, off));
    float e = __expf(v - mx);
    float sum = e;
#pragma unroll
    for (int off = 1; off < 16; off <<= 1) sum += __shfl_xor(sum, off);
    p[r] = e / sum;
  }

  // --- transpose P to A-layout via LDS ---
  uint16_t* pb = plds[wave];
#pragma unroll
  for (int r = 0; r < 4; ++r) pb[(quad * 4 + r) * 16 + l16] = f2bf(p[r]);
  __syncthreads();
  s16x8 ap = (s16x8){0, 0, 0, 0, 0, 0, 0, 0};
  if (quad < 2) ap = *(const s16x8*)&pb[l16 * 16 + quad * 8];  // P[l16][quad*8+j]

  // --- V B-frags from LDS: bv[c][j] = V[g=quad*8+j][d=c*16+l16] ---
  s16x8 bv[4];
#pragma unroll
  for (int c = 0; c < 4; ++c) bv[c] = (s16x8){0, 0, 0, 0, 0, 0, 0, 0};
  if (quad < 2) {
    const uint16_t* vl = vlds[wave];
#pragma unroll
    for (int c = 0; c < 4; ++c) {
      const int cc = c * 2 + (l16 >> 3);
      const int dlo = l16 & 7;
#pragma unroll
      for (int j = 0; j < 8; ++j) {
        const int g = quad * 8 + j;
        const int cs = cc ^ (2 * (g >> 3));
        bv[c][j] = (short)vl[g * 64 + cs * 8 + dlo];
      }
    }
  }

  // --- X = P V (16x64) ---
  f32x4 xacc[4];
#pragma unroll
  for (int c = 0; c < 4; ++c) {
    xacc[c] = (f32x4){0.f, 0.f, 0.f, 0.f};
    xacc[c] = __builtin_amdgcn_mfma_f32_16x16x32_bf16(ap, bv[c], xacc[c], 0, 0, 0);
  }

  // --- store: lane has x[h=quad*4+r][d=c*16+l16] ---
  uint16_t* xout =
      x2b + (size_t)b * (2048 * 1024) + (size_t)(n & 15) * 64 + (size_t)(n >> 4) * 1024;
#pragma unroll
  for (int c = 0; c < 4; ++c) {
    const int d = c * 16 + l16;
#pragma unroll
    for (int r = 0; r < 4; ++r) {
      const int h = quad * 4 + r;
      xout[(size_t)h * 128 * 1024 + d] = f2bf(xacc[c][r]);
    }
  }
}

// ---------------------------------------------------------------------------
extern "C" void kernel_launch(void* const* d_in, const int* in_sizes, int n_in,
                              void* d_out, int out_size, void* d_ws, size_t ws_size,
                              hipStream_t stream) {
  const float* query = (const float*)d_in[0];
  const float* key = (const float*)d_in[1];
  const float* value = (const float*)d_in[2];
  // d_in[3]=xpos, d_in[4]=ypos unused (rope is None)
  const float* Wq = (const float*)d_in[5];
  const float* Wk = (const float*)d_in[6];
  const float* Wv = (const float*)d_in[7];
  const float* Wp = (const float*)d_in[8];
  const float* bp = (const float*)d_in[9];
  float* out = (float*)d_out;

  const int C = 1024;
  const int M = 8 * 2048;  // 16384 tokens
  const size_t MC = (size_t)M * C;
  const size_t CC = (size_t)C * C;

  // workspace layout (bf16 = uint16), 200 MiB total:
  //   qb,kb,vb,x2b (4x32 MiB projected/attn buffers)
  //   wqb..wpb     (4x2 MiB weights)
  //   kin,vin      (2x32 MiB bf16 input copies)
  //   qin ALIASES x2b: x2b is dead until attn_kernel writes it, qin is dead
  //   after the QKV GEMM reads it; kernels serialize on the stream.
  uint16_t* ws = (uint16_t*)d_ws;
  uint16_t* qb = ws;
  uint16_t* kb = qb + MC;
  uint16_t* vb = kb + MC;
  uint16_t* x2b = vb + MC;
  uint16_t* wqb = x2b + MC;
  uint16_t* wkb = wqb + CC;
  uint16_t* wvb = wkb + CC;
  uint16_t* wpb = wvb + CC;
  uint16_t* kin = wpb + CC;
  uint16_t* vin = kin + MC;
  uint16_t* qin = x2b;  // alias (see above)

  // convert q/k/v inputs + all 4 weights to bf16 in one launch
  // threads: 3*2M (inputs) + 4*128K (weights) = 6815744 = 26624 * 256
  cvt_all_kernel<<<dim3(26624), dim3(256), 0, stream>>>(
      query, key, value, Wq, Wk, Wv, Wp, qin, kin, vin, wqb, wkb, wvb, wpb);

  // batched QKV projections, pure bf16 gload_lds path
  GemmBatch qkv;
  qkv.A[0] = qin;  qkv.B[0] = wqb;  qkv.C[0] = qb;
  qkv.A[1] = kin;  qkv.B[1] = wkb;  qkv.C[1] = kb;
  qkv.A[2] = vin;  qkv.B[2] = wvb;  qkv.C[2] = vb;
  gemm_bt<true><<<dim3((M / 128) * (C / 128) * 3), dim3(256), 0, stream>>>(qkv, nullptr,
                                                                           M, C, C);

  attn_kernel<<<dim3(M / 4), dim3(256), 0, stream>>>(qb, kb, vb, x2b);

  GemmBatch fin;
  fin.A[0] = x2b;  fin.B[0] = wpb;  fin.C[0] = out;
  fin.A[1] = x2b;  fin.B[1] = wpb;  fin.C[1] = out;
  fin.A[2] = x2b;  fin.B[2] = wpb;  fin.C[2] = out;
  gemm_bt<false><<<dim3((M / 128) * (C / 128)), dim3(256), 0, stream>>>(fin, bp, M, C, C);
}

// Round 3
// 428.806 us; speedup vs baseline: 1.4458x; 1.0454x over previous
//
#include <hip/hip_runtime.h>
#include <stdint.h>

#define DEV __device__ __forceinline__

using f32x4 = __attribute__((ext_vector_type(4))) float;
using s16x8 = __attribute__((ext_vector_type(8))) short;

DEV uint16_t f2bf(float f) {
  union { float f; uint32_t u; } v; v.f = f;
  uint32_t r = v.u + 0x7fffu + ((v.u >> 16) & 1u);  // round-to-nearest-even
  return (uint16_t)(r >> 16);
}
DEV uint32_t pack2(float a, float b) {
  return (uint32_t)f2bf(a) | ((uint32_t)f2bf(b) << 16);
}

// async global->LDS, 16B per lane; LDS dest = wave-uniform base + lane*16
DEV void gload_lds16(const void* g, void* l) {
  __builtin_amdgcn_global_load_lds(
      (__attribute__((address_space(1))) void*)(void*)g,
      (__attribute__((address_space(3))) void*)l, 16, 0, 0);
}

// ---------------------------------------------------------------------------
// f32 -> bf16 conversion for q/k/v inputs (3 x 16M elems) AND the 4 weight
// matrices (4 x 1M elems), one launch. 32B read / 16B write per thread.
// ---------------------------------------------------------------------------
__global__ __launch_bounds__(256) void cvt_all_kernel(
    const float* __restrict__ q, const float* __restrict__ k,
    const float* __restrict__ v, const float* __restrict__ Wq,
    const float* __restrict__ Wk, const float* __restrict__ Wv,
    const float* __restrict__ Wp, uint16_t* __restrict__ qc,
    uint16_t* __restrict__ kc, uint16_t* __restrict__ vc,
    uint16_t* __restrict__ wqb, uint16_t* __restrict__ wkb,
    uint16_t* __restrict__ wvb, uint16_t* __restrict__ wpb) {
  const int idx = blockIdx.x * blockDim.x + threadIdx.x;
  const float* src;
  uint16_t* dst;
  int i;
  if (idx < 3 * 2097152) {  // inputs: 16M f32 each -> 2M threads each
    const int t = idx >> 21;
    i = idx & 2097151;
    src = t == 0 ? q : t == 1 ? k : v;
    dst = t == 0 ? qc : t == 1 ? kc : vc;
  } else {  // weights: 1M f32 each -> 128K threads each
    const int j = idx - 3 * 2097152;
    const int r = j >> 17;
    i = j & 131071;
    src = r == 0 ? Wq : r == 1 ? Wk : r == 2 ? Wv : Wp;
    dst = r == 0 ? wqb : r == 1 ? wkb : r == 2 ? wvb : wpb;
  }
  const float4* s = (const float4*)src;
  float4 a = s[2 * i];
  float4 b = s[2 * i + 1];
  uint4 pk;
  pk.x = pack2(a.x, a.y);
  pk.y = pack2(a.z, a.w);
  pk.z = pack2(b.x, b.y);
  pk.w = pack2(b.z, b.w);
  ((uint4*)dst)[i] = pk;
}

// ---------------------------------------------------------------------------
// NT GEMM, R3: deep-pipelined 256x256 tile, BK=32, 512 threads = 8 waves
// (2M x 4N), per-wave output 128x64 (8x4 fragments of 16x16).
//
// Pipeline (T3/T4): 4-deep circular LDS buffer (4 x (A 16KB + B 16KB) =
// 128 KB). Iter t computes K-tile t from buf (t&3) and stages K-tile t+3
// into buf ((t+3)&3) = ((t-1)&3) -- the buffer whose reads all completed
// before this iteration's barrier (each wave's ds_reads are consumed by its
// pre-barrier MFMAs). Counted s_waitcnt vmcnt(8) before the ONE raw
// s_barrier per K-tile: tile t's loads landed, tiles t+1/t+2's 8 loads stay
// in flight across the barrier (NEVER vmcnt(0) mid-loop -- R1's regression
// was __syncthreads' implicit vmcnt(0) drain killing the prefetch).
// sched_barrier(0) after the s_barrier pins ds_reads below it (other waves'
// stage-writes are only guaranteed visible after the barrier).
//
// LDS 16B-chunk XOR swizzle pc = c ^ ((row>>1)&3): measured 0 bank conflicts
// at this pattern (R0-R2). XCD-stripe swizzle for A-panel L2 reuse kept.
// T5 setprio wraps each 8-MFMA cluster (phase-split schedule -> role
// diversity, per m218b).
// ---------------------------------------------------------------------------
struct GemmBatch {
  const uint16_t* A[3];
  const uint16_t* B[3];
  void* C[3];
};

template <bool OUT_BF16>
__global__ __launch_bounds__(512, 2) void gemm_bt256(GemmBatch gb,
                                                     const float* __restrict__ bias,
                                                     int M, int N, int K) {
  constexpr int BM = 256, BN = 256, BK = 32;
  // 4 buffers x (A 256x32 + B 256x32) bf16 = 4 x 32 KB = 128 KB
  __shared__ __align__(16) uint16_t Alds[4][BM * BK];
  __shared__ __align__(16) uint16_t Blds[4][BN * BK];

  // XCD-stripe decode: w = xcd + 8*(bn + nbn*(bml + bmpx*z))
  const int w = blockIdx.x;
  const int xcd = w & 7;
  int local = w >> 3;
  const int nbn = N >> 8;
  const int bmpx = (M >> 8) >> 3;
  const int bn = local % nbn;
  local /= nbn;
  const int bml = local % bmpx;
  const int z = local / bmpx;
  const int bm0 = (xcd * bmpx + bml) * BM;
  const int bn0 = bn * BN;

  const uint16_t* __restrict__ Ap = gb.A[z];
  const uint16_t* __restrict__ Bp = gb.B[z];
  void* __restrict__ Cp = gb.C[z];

  const int tid = threadIdx.x;
  const int wave = tid >> 6;
  const int lane = tid & 63;
  const int quad = lane >> 4;
  const int l16 = lane & 15;
  const int wm = (wave >> 2) * 128;  // 2 wave-rows
  const int wn = (wave & 3) * 64;   // 4 wave-cols

  f32x4 acc[8][4];
#pragma unroll
  for (int i = 0; i < 8; ++i)
#pragma unroll
    for (int j = 0; j < 4; ++j) acc[i][j] = (f32x4){0.f, 0.f, 0.f, 0.f};

  // staging: tile = 256 rows x 4 chunks(16B) = 1024 chunks; wave handles
  // chunks wave*128 + j*64 + lane (j=0,1), for A and B each (4 gloads/thread
  // per K-tile). Source column-chunk pre-swizzled (involution) so linear LDS
  // dest + swizzled ds_read retrieve the right data (rule #21).
  const uint16_t* asrc[2];
  const uint16_t* bsrc[2];
  int sofs[2];  // ushort offset of the wave-uniform LDS dest base
#pragma unroll
  for (int j = 0; j < 2; ++j) {
    const int p = wave * 128 + j * 64 + lane;
    const int m = p >> 2;
    const int c = p & 3;
    const int lc = c ^ ((m >> 1) & 3);
    asrc[j] = Ap + (size_t)(bm0 + m) * K + lc * 8;
    bsrc[j] = Bp + (size_t)(bn0 + m) * K + lc * 8;
    sofs[j] = (wave * 128 + j * 64) * 8;
  }

  const int NT = K >> 5;  // K-tiles of 32; requires NT >= 3 (K=1024 -> 32)

  // ---- prologue: stage tiles 0..2 (12 gloads/thread in flight) ----
#pragma unroll
  for (int tt = 0; tt < 3; ++tt) {
#pragma unroll
    for (int j = 0; j < 2; ++j) gload_lds16(asrc[j] + tt * BK, &Alds[tt][sofs[j]]);
#pragma unroll
    for (int j = 0; j < 2; ++j) gload_lds16(bsrc[j] + tt * BK, &Blds[tt][sofs[j]]);
  }

  for (int t = 0; t < NT; ++t) {
    const int buf = t & 3;
    // counted wait: own tile-t loads (4) landed; up to 8 newer stay in flight
    if (t + 2 < NT) {
      asm volatile("s_waitcnt vmcnt(8)" ::: "memory");
    } else if (t + 1 < NT) {
      asm volatile("s_waitcnt vmcnt(4)" ::: "memory");
    } else {
      asm volatile("s_waitcnt vmcnt(0)" ::: "memory");
    }
    __builtin_amdgcn_s_barrier();          // all waves' tile-t data visible
    __builtin_amdgcn_sched_barrier(0);     // pin: no ds_read hoists above

    // stage tile t+3 into buf (t+3)&3 == (t-1)&3 (reads of it all done)
    if (t + 3 < NT) {
      const int sb = (t + 3) & 3;
      const int ko = (t + 3) * BK;
#pragma unroll
      for (int j = 0; j < 2; ++j) gload_lds16(asrc[j] + ko, &Alds[sb][sofs[j]]);
#pragma unroll
      for (int j = 0; j < 2; ++j) gload_lds16(bsrc[j] + ko, &Blds[sb][sofs[j]]);
    }

    // B fragments for this K-tile (4 x ds_read_b128)
    s16x8 bf[4];
#pragma unroll
    for (int nf = 0; nf < 4; ++nf) {
      const int nl = wn + nf * 16 + l16;
      const int cb = nl * 4 + (quad ^ ((nl >> 1) & 3));
      bf[nf] = *(const s16x8*)&Blds[buf][cb * 8];
    }

    // 4 phases: {2 A ds_reads; setprio(1); 8 MFMA; setprio(0)}
#pragma unroll
    for (int ph = 0; ph < 4; ++ph) {
      const int ml0 = wm + (ph * 2) * 16 + l16;
      const int ca0 = ml0 * 4 + (quad ^ ((ml0 >> 1) & 3));
      s16x8 af0 = *(const s16x8*)&Alds[buf][ca0 * 8];
      const int ml1 = wm + (ph * 2 + 1) * 16 + l16;
      const int ca1 = ml1 * 4 + (quad ^ ((ml1 >> 1) & 3));
      s16x8 af1 = *(const s16x8*)&Alds[buf][ca1 * 8];
      __builtin_amdgcn_s_setprio(1);
#pragma unroll
      for (int nf = 0; nf < 4; ++nf) {
        acc[ph * 2][nf] =
            __builtin_amdgcn_mfma_f32_16x16x32_bf16(af0, bf[nf], acc[ph * 2][nf], 0, 0, 0);
        acc[ph * 2 + 1][nf] =
            __builtin_amdgcn_mfma_f32_16x16x32_bf16(af1, bf[nf], acc[ph * 2 + 1][nf], 0, 0, 0);
      }
      __builtin_amdgcn_s_setprio(0);
    }
  }

  // epilogue: C/D layout col = lane&15, row = quad*4 + r (m89-verified)
#pragma unroll
  for (int sm = 0; sm < 8; ++sm) {
    const int mrow = bm0 + wm + sm * 16 + quad * 4;
#pragma unroll
    for (int sn = 0; sn < 4; ++sn) {
      const int ncol = bn0 + wn + sn * 16 + l16;
      if constexpr (OUT_BF16) {
        uint16_t* Cb = (uint16_t*)Cp;
#pragma unroll
        for (int r = 0; r < 4; ++r) Cb[(size_t)(mrow + r) * N + ncol] = f2bf(acc[sm][sn][r]);
      } else {
        float* Cf = (float*)Cp;
        const float bv = bias[ncol];
#pragma unroll
        for (int r = 0; r < 4; ++r) Cf[(size_t)(mrow + r) * N + ncol] = acc[sm][sn][r] + bv;
      }
    }
  }
}

// ---------------------------------------------------------------------------
// MFMA attention: one WAVE per token. S = Q·K^T via 2x mfma_16x16x32_bf16;
// softmax over g via shfl_xor within 16-lane groups; P through 512B LDS to
// A-layout; V staged coalesced into an XOR-swizzled LDS tile; PV = 4x
// zero-padded mfma_16x16x32.
// Store into "buggy reshape" position X2[b, h*128 + n/16, (n%16)*64 + d].
// ---------------------------------------------------------------------------
__global__ __launch_bounds__(256) void attn_kernel(const uint16_t* __restrict__ qb,
                                                   const uint16_t* __restrict__ kb,
                                                   const uint16_t* __restrict__ vb,
                                                   uint16_t* __restrict__ x2b) {
  __shared__ __align__(16) uint16_t plds[4][16 * 16];  // per-wave P (16x16 bf16)
  __shared__ __align__(16) uint16_t vlds[4][16 * 64];  // per-wave V tile, swizzled

  const int tid = threadIdx.x;
  const int wave = tid >> 6;
  const int lane = tid & 63;
  const int quad = lane >> 4;
  const int l16 = lane & 15;
  const int token = blockIdx.x * 4 + wave;
  const int b = token >> 11;
  const int n = token & 2047;
  const size_t base = (size_t)token * 1024;

  // --- stage V (coalesced 16B chunks, XOR-swizzled columns) ---
  {
    const uint16_t* vt = vb + base;  // 16x64 bf16, contiguous
    uint16_t* vl = vlds[wave];
#pragma unroll
    for (int c2 = 0; c2 < 2; ++c2) {
      const int p = lane + c2 * 64;  // chunk index; src = 16B at p*16
      const int g = p >> 3;
      const int cc = p & 7;
      const int cs = cc ^ (2 * (g >> 3));
      *(uint4*)&vl[g * 64 + cs * 8] = *(const uint4*)&vt[p * 8];
    }
  }

  // --- S = Q K^T (16x16, K=64) ---
  const uint16_t* qrow = qb + base + l16 * 64 + quad * 8;
  const uint16_t* krow = kb + base + l16 * 64 + quad * 8;
  s16x8 aq0 = *(const s16x8*)qrow;
  s16x8 aq1 = *(const s16x8*)(qrow + 32);
  s16x8 bk0 = *(const s16x8*)krow;
  s16x8 bk1 = *(const s16x8*)(krow + 32);
  f32x4 s = (f32x4){0.f, 0.f, 0.f, 0.f};
  s = __builtin_amdgcn_mfma_f32_16x16x32_bf16(aq0, bk0, s, 0, 0, 0);
  s = __builtin_amdgcn_mfma_f32_16x16x32_bf16(aq1, bk1, s, 0, 0, 0);
  // lane holds S[h=quad*4+r][g=l16], r=0..3

  // --- softmax over g (across the 16 lanes sharing quad) ---
  float p[4];
#pragma unroll
  for (int r = 0; r < 4; ++r) {
    float v = s[r] * 0.125f;  // SCALE = 64^-0.5
    float mx = v;
#pragma unroll
    for (int off = 1; off < 16; off <<= 1) mx = fmaxf(mx, __shfl_xor(mx, off));
    float e = __expf(v - mx);
    float sum = e;
#pragma unroll
    for (int off = 1; off < 16; off <<= 1) sum += __shfl_xor(sum, off);
    p[r] = e / sum;
  }

  // --- transpose P to A-layout via LDS ---
  uint16_t* pb = plds[wave];
#pragma unroll
  for (int r = 0; r < 4; ++r) pb[(quad * 4 + r) * 16 + l16] = f2bf(p[r]);
  __syncthreads();
  s16x8 ap = (s16x8){0, 0, 0, 0, 0, 0, 0, 0};
  if (quad < 2) ap = *(const s16x8*)&pb[l16 * 16 + quad * 8];  // P[l16][quad*8+j]

  // --- V B-frags from LDS: bv[c][j] = V[g=quad*8+j][d=c*16+l16] ---
  s16x8 bv[4];
#pragma unroll
  for (int c = 0; c < 4; ++c) bv[c] = (s16x8){0, 0, 0, 0, 0, 0, 0, 0};
  if (quad < 2) {
    const uint16_t* vl = vlds[wave];
#pragma unroll
    for (int c = 0; c < 4; ++c) {
      const int cc = c * 2 + (l16 >> 3);
      const int dlo = l16 & 7;
#pragma unroll
      for (int j = 0; j < 8; ++j) {
        const int g = quad * 8 + j;
        const int cs = cc ^ (2 * (g >> 3));
        bv[c][j] = (short)vl[g * 64 + cs * 8 + dlo];
      }
    }
  }

  // --- X = P V (16x64) ---
  f32x4 xacc[4];
#pragma unroll
  for (int c = 0; c < 4; ++c) {
    xacc[c] = (f32x4){0.f, 0.f, 0.f, 0.f};
    xacc[c] = __builtin_amdgcn_mfma_f32_16x16x32_bf16(ap, bv[c], xacc[c], 0, 0, 0);
  }

  // --- store: lane has x[h=quad*4+r][d=c*16+l16] ---
  uint16_t* xout =
      x2b + (size_t)b * (2048 * 1024) + (size_t)(n & 15) * 64 + (size_t)(n >> 4) * 1024;
#pragma unroll
  for (int c = 0; c < 4; ++c) {
    const int d = c * 16 + l16;
#pragma unroll
    for (int r = 0; r < 4; ++r) {
      const int h = quad * 4 + r;
      xout[(size_t)h * 128 * 1024 + d] = f2bf(xacc[c][r]);
    }
  }
}

// ---------------------------------------------------------------------------
extern "C" void kernel_launch(void* const* d_in, const int* in_sizes, int n_in,
                              void* d_out, int out_size, void* d_ws, size_t ws_size,
                              hipStream_t stream) {
  const float* query = (const float*)d_in[0];
  const float* key = (const float*)d_in[1];
  const float* value = (const float*)d_in[2];
  // d_in[3]=xpos, d_in[4]=ypos unused (rope is None)
  const float* Wq = (const float*)d_in[5];
  const float* Wk = (const float*)d_in[6];
  const float* Wv = (const float*)d_in[7];
  const float* Wp = (const float*)d_in[8];
  const float* bp = (const float*)d_in[9];
  float* out = (float*)d_out;

  const int C = 1024;
  const int M = 8 * 2048;  // 16384 tokens
  const size_t MC = (size_t)M * C;
  const size_t CC = (size_t)C * C;

  // workspace layout (bf16 = uint16), 200 MiB total:
  //   qb,kb,vb,x2b (4x32 MiB), wqb..wpb (4x2 MiB), kin,vin (2x32 MiB)
  //   qin ALIASES x2b (x2b dead until attn; qin dead after QKV GEMM).
  uint16_t* ws = (uint16_t*)d_ws;
  uint16_t* qb = ws;
  uint16_t* kb = qb + MC;
  uint16_t* vb = kb + MC;
  uint16_t* x2b = vb + MC;
  uint16_t* wqb = x2b + MC;
  uint16_t* wkb = wqb + CC;
  uint16_t* wvb = wkb + CC;
  uint16_t* wpb = wvb + CC;
  uint16_t* kin = wpb + CC;
  uint16_t* vin = kin + MC;
  uint16_t* qin = x2b;  // alias (see above)

  // convert q/k/v inputs + all 4 weights to bf16 in one launch
  cvt_all_kernel<<<dim3(26624), dim3(256), 0, stream>>>(
      query, key, value, Wq, Wk, Wv, Wp, qin, kin, vin, wqb, wkb, wvb, wpb);

  // batched QKV projections: 256x256 tiles, grid = 64 m * 4 n * 3 = 768
  GemmBatch qkv;
  qkv.A[0] = qin;  qkv.B[0] = wqb;  qkv.C[0] = qb;
  qkv.A[1] = kin;  qkv.B[1] = wkb;  qkv.C[1] = kb;
  qkv.A[2] = vin;  qkv.B[2] = wvb;  qkv.C[2] = vb;
  gemm_bt256<true><<<dim3((M / 256) * (C / 256) * 3), dim3(512), 0, stream>>>(
      qkv, nullptr, M, C, C);

  attn_kernel<<<dim3(M / 4), dim3(256), 0, stream>>>(qb, kb, vb, x2b);

  GemmBatch fin;
  fin.A[0] = x2b;  fin.B[0] = wpb;  fin.C[0] = out;
  fin.A[1] = x2b;  fin.B[1] = wpb;  fin.C[1] = out;
  fin.A[2] = x2b;  fin.B[2] = wpb;  fin.C[2] = out;
  gemm_bt256<false><<<dim3((M / 256) * (C / 256)), dim3(512), 0, stream>>>(fin, bp, M,
                                                                           C, C);
}

// Round 4
// 392.369 us; speedup vs baseline: 1.5801x; 1.0929x over previous
//
#include <hip/hip_runtime.h>
#include <stdint.h>

#define DEV __device__ __forceinline__

using f32x4 = __attribute__((ext_vector_type(4))) float;
using s16x8 = __attribute__((ext_vector_type(8))) short;

DEV uint16_t f2bf(float f) {
  union { float f; uint32_t u; } v; v.f = f;
  uint32_t r = v.u + 0x7fffu + ((v.u >> 16) & 1u);  // round-to-nearest-even
  return (uint16_t)(r >> 16);
}
DEV uint32_t pack2(float a, float b) {
  return (uint32_t)f2bf(a) | ((uint32_t)f2bf(b) << 16);
}

// async global->LDS, 16B per lane; LDS dest = wave-uniform base + lane*16
DEV void gload_lds16(const void* g, void* l) {
  __builtin_amdgcn_global_load_lds(
      (__attribute__((address_space(1))) void*)(void*)g,
      (__attribute__((address_space(3))) void*)l, 16, 0, 0);
}

// ---------------------------------------------------------------------------
// f32 -> bf16 conversion for q/k/v inputs (3 x 16M elems) AND the 4 weight
// matrices (4 x 1M elems), one launch. 32B read / 16B write per thread.
// ---------------------------------------------------------------------------
__global__ __launch_bounds__(256) void cvt_all_kernel(
    const float* __restrict__ q, const float* __restrict__ k,
    const float* __restrict__ v, const float* __restrict__ Wq,
    const float* __restrict__ Wk, const float* __restrict__ Wv,
    const float* __restrict__ Wp, uint16_t* __restrict__ qc,
    uint16_t* __restrict__ kc, uint16_t* __restrict__ vc,
    uint16_t* __restrict__ wqb, uint16_t* __restrict__ wkb,
    uint16_t* __restrict__ wvb, uint16_t* __restrict__ wpb) {
  const int idx = blockIdx.x * blockDim.x + threadIdx.x;
  const float* src;
  uint16_t* dst;
  int i;
  if (idx < 3 * 2097152) {  // inputs: 16M f32 each -> 2M threads each
    const int t = idx >> 21;
    i = idx & 2097151;
    src = t == 0 ? q : t == 1 ? k : v;
    dst = t == 0 ? qc : t == 1 ? kc : vc;
  } else {  // weights: 1M f32 each -> 128K threads each
    const int j = idx - 3 * 2097152;
    const int r = j >> 17;
    i = j & 131071;
    src = r == 0 ? Wq : r == 1 ? Wk : r == 2 ? Wv : Wp;
    dst = r == 0 ? wqb : r == 1 ? wkb : r == 2 ? wvb : wpb;
  }
  const float4* s = (const float4*)src;
  float4 a = s[2 * i];
  float4 b = s[2 * i + 1];
  uint4 pk;
  pk.x = pack2(a.x, a.y);
  pk.y = pack2(a.z, a.w);
  pk.z = pack2(b.x, b.y);
  pk.w = pack2(b.z, b.w);
  ((uint4*)dst)[i] = pk;
}

// ---------------------------------------------------------------------------
// NT GEMM, R4: faithful 8-phase schedule (m201 template, T3+T4+T5).
// 256x256 tile, BK=64, 512 threads = 8 waves (2M x 4N), per-wave 128x64.
// LDS: 2 double-buffers x (A 256x64 + B 256x64) bf16 = 128 KB.
//
// Iteration i computes K-tiles t0=2i (buf0) and t1=2i+1 (buf1) in 8 phases.
// Phase = { ds_read quadrant frags ; stage 1 half-tile (2 gloads) ;
//           s_barrier ; lgkmcnt(0) ; setprio(1) ; 16 MFMA ; setprio(0) ;
//           s_barrier }.
// Quadrants per tile: (mh,nh) in order (0,0),(0,1),(1,0),(1,1); A-half
// loaded at quadrants (0,0)/(1,0) (8 ds_read_b128), B-halves at (0,0)/(0,1)
// (4 each), B regs stay live across the tile.
//
// Stage schedule (half-tile = one matrix's 128 LDS rows = 2 gloads/thread):
//   ph0: A0(t1)->buf1   ph1: A1(t1)->buf1   ph2: B0(t0+2)->buf0
//   ph3: B1(t0+2)->buf0 ph4: A0(t0+2)->buf0 ph5: A1(t0+2)->buf0
//   ph6: B0(t1+2)->buf1 ph7: B1(t1+2)->buf1
// Safety: each staged region was last ds_read >=1 closing-barrier earlier
// (closing barrier of phase p implies every wave completed its phase-p
// lgkmcnt(0), i.e. its reads). E.g. buf0 B rows last read ph1 -> staged
// ph2/ph3; buf0 A rows last read ph2 -> staged ph4/ph5.
//
// vmcnt discipline (T4): counted waits ONLY at the END of ph3 and ph7,
// BEFORE the closing barrier -- the barrier then broadcasts the per-wave
// guarantee to all waves (vmcnt is per-wave; R3 waited AFTER the barrier
// before its own reads, which protected nothing of other waves' stages).
//   ph3 end: vmcnt(4) -> all but {B0,B1}(t0+2) landed => A(t1) in LDS,
//            ph4 reads of buf1 safe.  Final iter: those 4 newest ARE A(t1)
//            -> vmcnt(0).
//   ph7 end: vmcnt(4) -> all but {B0,B1}(t1+2) landed => tile t0+2 fully
//            in buf0 for next iteration's ph0.
// Never vmcnt(0) mid-loop: 2 half-tiles (4 loads) always stay in flight.
//
// LDS 16B-chunk XOR swizzle (3-bit): global chunk (m, c^((m>>1)&7)) stored
// at linear chunk m*8+c (pre-swizzled source address, rule #21); frag read
// uses chunk m*8 + ((k*4+quad)^((m>>1)&7)). Same family as the measured-
// 0-conflict BK=32 scheme. XCD-stripe swizzle kept.
// ---------------------------------------------------------------------------
struct GemmBatch {
  const uint16_t* A[3];
  const uint16_t* B[3];
  void* C[3];
};

template <bool OUT_BF16>
__global__ __launch_bounds__(512, 2) void gemm8p(GemmBatch gb,
                                                 const float* __restrict__ bias,
                                                 int M, int N, int K) {
  constexpr int BM = 256, BN = 256, BK = 64;
  __shared__ __align__(16) uint16_t Alds[2][BM * BK];  // 2 x 32 KB
  __shared__ __align__(16) uint16_t Blds[2][BN * BK];  // 2 x 32 KB

  // XCD-stripe decode: w = xcd + 8*(bn + nbn*(bml + bmpx*z))
  const int w = blockIdx.x;
  const int xcd = w & 7;
  int local = w >> 3;
  const int nbn = N >> 8;
  const int bmpx = (M >> 8) >> 3;
  const int bn = local % nbn;
  local /= nbn;
  const int bml = local % bmpx;
  const int z = local / bmpx;
  const int bm0 = (xcd * bmpx + bml) * BM;
  const int bn0 = bn * BN;

  const uint16_t* __restrict__ Ap = gb.A[z];
  const uint16_t* __restrict__ Bp = gb.B[z];
  void* __restrict__ Cp = gb.C[z];

  const int tid = threadIdx.x;
  const int wave = tid >> 6;
  const int lane = tid & 63;
  const int quad = lane >> 4;
  const int l16 = lane & 15;
  const int wm = (wave >> 2) * 128;  // 2 wave-rows
  const int wn = (wave & 3) * 64;   // 4 wave-cols

  f32x4 acc[8][4];
#pragma unroll
  for (int i = 0; i < 8; ++i)
#pragma unroll
    for (int j = 0; j < 4; ++j) acc[i][j] = (f32x4){0.f, 0.f, 0.f, 0.f};

  // staging precompute: half h (LDS rows h*128..h*128+127), load j:
  // chunk p = h*1024 + wave*128 + j*64 + lane; m=p>>3; c=p&7; src col
  // chunk lc = c ^ ((m>>1)&7) (pre-swizzle involution).
  size_t aofs[2][2], bofs[2][2];
  int lofs[2][2];
#pragma unroll
  for (int h = 0; h < 2; ++h)
#pragma unroll
    for (int j = 0; j < 2; ++j) {
      const int p = h * 1024 + wave * 128 + j * 64 + lane;
      const int m = p >> 3;
      const int lc = (p & 7) ^ ((m >> 1) & 7);
      aofs[h][j] = (size_t)(bm0 + m) * K + lc * 8;
      bofs[h][j] = (size_t)(bn0 + m) * K + lc * 8;
      lofs[h][j] = (h * 1024 + wave * 128 + j * 64) * 8;  // wave-uniform
    }

  auto SA = [&](int tile, int h) {
    uint16_t* base = Alds[tile & 1];
#pragma unroll
    for (int j = 0; j < 2; ++j)
      gload_lds16(Ap + aofs[h][j] + (size_t)tile * BK, base + lofs[h][j]);
  };
  auto SB = [&](int tile, int h) {
    uint16_t* base = Blds[tile & 1];
#pragma unroll
    for (int j = 0; j < 2; ++j)
      gload_lds16(Bp + bofs[h][j] + (size_t)tile * BK, base + lofs[h][j]);
  };

  s16x8 Af[4][2], Bf[4][2];
  auto LDA = [&](int buf, int mh) {
#pragma unroll
    for (int s = 0; s < 4; ++s) {
      const int ml = wm + (mh * 4 + s) * 16 + l16;
      const int sw = (ml >> 1) & 7;
#pragma unroll
      for (int k = 0; k < 2; ++k) {
        const int cc = ml * 8 + ((k * 4 + quad) ^ sw);
        Af[s][k] = *(const s16x8*)&Alds[buf][cc * 8];
      }
    }
  };
  auto LDB = [&](int buf, int nh) {
#pragma unroll
    for (int s = 0; s < 2; ++s) {
      const int nl = wn + (nh * 2 + s) * 16 + l16;
      const int sw = (nl >> 1) & 7;
#pragma unroll
      for (int k = 0; k < 2; ++k) {
        const int cc = nl * 8 + ((k * 4 + quad) ^ sw);
        Bf[nh * 2 + s][k] = *(const s16x8*)&Blds[buf][cc * 8];
      }
    }
  };
  auto OPEN = [&]() {
    __builtin_amdgcn_s_barrier();
    asm volatile("s_waitcnt lgkmcnt(0)" ::: "memory");
    __builtin_amdgcn_sched_barrier(0);
  };
  auto MMA = [&](int mh, int nh) {
    __builtin_amdgcn_s_setprio(1);
#pragma unroll
    for (int s = 0; s < 4; ++s)
#pragma unroll
      for (int n = 0; n < 2; ++n)
#pragma unroll
        for (int k = 0; k < 2; ++k)
          acc[mh * 4 + s][nh * 2 + n] = __builtin_amdgcn_mfma_f32_16x16x32_bf16(
              Af[s][k], Bf[nh * 2 + n][k], acc[mh * 4 + s][nh * 2 + n], 0, 0, 0);
    __builtin_amdgcn_s_setprio(0);
  };
  auto CLOSE = [&]() { __builtin_amdgcn_s_barrier(); };

  const int NT = K >> 6;   // 16 K-tiles (K=1024)
  const int NI = NT >> 1;  // 8 iterations

  // prologue: tile0 fully -> buf0; tile1's B halves -> buf1 (12 gloads)
  SA(0, 0); SA(0, 1); SB(0, 0); SB(0, 1); SB(1, 0); SB(1, 1);
  asm volatile("s_waitcnt vmcnt(4)" ::: "memory");  // tile0's 8 landed
  __builtin_amdgcn_s_barrier();

  for (int i = 0; i < NI; ++i) {
    const int t0 = 2 * i, t1 = 2 * i + 1;
    const bool more = (t0 + 2 < NT);  // block-uniform

    // ph0: tile t0 quadrant (0,0)
    LDA(0, 0); LDB(0, 0);
    SA(t1, 0);
    OPEN(); MMA(0, 0); CLOSE();
    // ph1: quadrant (0,1)
    LDB(0, 1);
    SA(t1, 1);
    OPEN(); MMA(0, 1); CLOSE();
    // ph2: quadrant (1,0)
    LDA(0, 1);
    if (more) SB(t0 + 2, 0);
    OPEN(); MMA(1, 0); CLOSE();
    // ph3: quadrant (1,1); counted vmcnt BEFORE closing barrier
    if (more) SB(t0 + 2, 1);
    OPEN(); MMA(1, 1);
    if (more) asm volatile("s_waitcnt vmcnt(4)" ::: "memory");
    else      asm volatile("s_waitcnt vmcnt(0)" ::: "memory");
    CLOSE();

    // ph4: tile t1 quadrant (0,0)
    LDA(1, 0); LDB(1, 0);
    if (more) SA(t0 + 2, 0);
    OPEN(); MMA(0, 0); CLOSE();
    // ph5: quadrant (0,1)
    LDB(1, 1);
    if (more) SA(t0 + 2, 1);
    OPEN(); MMA(0, 1); CLOSE();
    // ph6: quadrant (1,0)
    LDA(1, 1);
    if (more) SB(t1 + 2, 0);
    OPEN(); MMA(1, 0); CLOSE();
    // ph7: quadrant (1,1); counted vmcnt BEFORE closing barrier
    if (more) SB(t1 + 2, 1);
    OPEN(); MMA(1, 1);
    asm volatile("s_waitcnt vmcnt(4)" ::: "memory");
    CLOSE();
  }

  // epilogue: C/D layout col = lane&15, row = quad*4 + r (m89-verified)
#pragma unroll
  for (int sm = 0; sm < 8; ++sm) {
    const int mrow = bm0 + wm + sm * 16 + quad * 4;
#pragma unroll
    for (int sn = 0; sn < 4; ++sn) {
      const int ncol = bn0 + wn + sn * 16 + l16;
      if constexpr (OUT_BF16) {
        uint16_t* Cb = (uint16_t*)Cp;
#pragma unroll
        for (int r = 0; r < 4; ++r) Cb[(size_t)(mrow + r) * N + ncol] = f2bf(acc[sm][sn][r]);
      } else {
        float* Cf = (float*)Cp;
        const float bv = bias[ncol];
#pragma unroll
        for (int r = 0; r < 4; ++r) Cf[(size_t)(mrow + r) * N + ncol] = acc[sm][sn][r] + bv;
      }
    }
  }
}

// ---------------------------------------------------------------------------
// MFMA attention: one WAVE per token. S = Q·K^T via 2x mfma_16x16x32_bf16;
// softmax over g via shfl_xor within 16-lane groups; P through 512B LDS to
// A-layout; V staged coalesced into an XOR-swizzled LDS tile; PV = 4x
// zero-padded mfma_16x16x32.
// Store into "buggy reshape" position X2[b, h*128 + n/16, (n%16)*64 + d].
// ---------------------------------------------------------------------------
__global__ __launch_bounds__(256) void attn_kernel(const uint16_t* __restrict__ qb,
                                                   const uint16_t* __restrict__ kb,
                                                   const uint16_t* __restrict__ vb,
                                                   uint16_t* __restrict__ x2b) {
  __shared__ __align__(16) uint16_t plds[4][16 * 16];  // per-wave P (16x16 bf16)
  __shared__ __align__(16) uint16_t vlds[4][16 * 64];  // per-wave V tile, swizzled

  const int tid = threadIdx.x;
  const int wave = tid >> 6;
  const int lane = tid & 63;
  const int quad = lane >> 4;
  const int l16 = lane & 15;
  const int token = blockIdx.x * 4 + wave;
  const int b = token >> 11;
  const int n = token & 2047;
  const size_t base = (size_t)token * 1024;

  // --- stage V (coalesced 16B chunks, XOR-swizzled columns) ---
  {
    const uint16_t* vt = vb + base;  // 16x64 bf16, contiguous
    uint16_t* vl = vlds[wave];
#pragma unroll
    for (int c2 = 0; c2 < 2; ++c2) {
      const int p = lane + c2 * 64;  // chunk index; src = 16B at p*16
      const int g = p >> 3;
      const int cc = p & 7;
      const int cs = cc ^ (2 * (g >> 3));
      *(uint4*)&vl[g * 64 + cs * 8] = *(const uint4*)&vt[p * 8];
    }
  }

  // --- S = Q K^T (16x16, K=64) ---
  const uint16_t* qrow = qb + base + l16 * 64 + quad * 8;
  const uint16_t* krow = kb + base + l16 * 64 + quad * 8;
  s16x8 aq0 = *(const s16x8*)qrow;
  s16x8 aq1 = *(const s16x8*)(qrow + 32);
  s16x8 bk0 = *(const s16x8*)krow;
  s16x8 bk1 = *(const s16x8*)(krow + 32);
  f32x4 s = (f32x4){0.f, 0.f, 0.f, 0.f};
  s = __builtin_amdgcn_mfma_f32_16x16x32_bf16(aq0, bk0, s, 0, 0, 0);
  s = __builtin_amdgcn_mfma_f32_16x16x32_bf16(aq1, bk1, s, 0, 0, 0);
  // lane holds S[h=quad*4+r][g=l16], r=0..3

  // --- softmax over g (across the 16 lanes sharing quad) ---
  float p[4];
#pragma unroll
  for (int r = 0; r < 4; ++r) {
    float v = s[r] * 0.125f;  // SCALE = 64^-0.5
    float mx = v;
#pragma unroll
    for (int off = 1; off < 16; off <<= 1) mx = fmaxf(mx, __shfl_xor(mx, off));
    float e = __expf(v - mx);
    float sum = e;
#pragma unroll
    for (int off = 1; off < 16; off <<= 1) sum += __shfl_xor(sum, off);
    p[r] = e / sum;
  }

  // --- transpose P to A-layout via LDS ---
  uint16_t* pb = plds[wave];
#pragma unroll
  for (int r = 0; r < 4; ++r) pb[(quad * 4 + r) * 16 + l16] = f2bf(p[r]);
  __syncthreads();
  s16x8 ap = (s16x8){0, 0, 0, 0, 0, 0, 0, 0};
  if (quad < 2) ap = *(const s16x8*)&pb[l16 * 16 + quad * 8];  // P[l16][quad*8+j]

  // --- V B-frags from LDS: bv[c][j] = V[g=quad*8+j][d=c*16+l16] ---
  s16x8 bv[4];
#pragma unroll
  for (int c = 0; c < 4; ++c) bv[c] = (s16x8){0, 0, 0, 0, 0, 0, 0, 0};
  if (quad < 2) {
    const uint16_t* vl = vlds[wave];
#pragma unroll
    for (int c = 0; c < 4; ++c) {
      const int cc = c * 2 + (l16 >> 3);
      const int dlo = l16 & 7;
#pragma unroll
      for (int j = 0; j < 8; ++j) {
        const int g = quad * 8 + j;
        const int cs = cc ^ (2 * (g >> 3));
        bv[c][j] = (short)vl[g * 64 + cs * 8 + dlo];
      }
    }
  }

  // --- X = P V (16x64) ---
  f32x4 xacc[4];
#pragma unroll
  for (int c = 0; c < 4; ++c) {
    xacc[c] = (f32x4){0.f, 0.f, 0.f, 0.f};
    xacc[c] = __builtin_amdgcn_mfma_f32_16x16x32_bf16(ap, bv[c], xacc[c], 0, 0, 0);
  }

  // --- store: lane has x[h=quad*4+r][d=c*16+l16] ---
  uint16_t* xout =
      x2b + (size_t)b * (2048 * 1024) + (size_t)(n & 15) * 64 + (size_t)(n >> 4) * 1024;
#pragma unroll
  for (int c = 0; c < 4; ++c) {
    const int d = c * 16 + l16;
#pragma unroll
    for (int r = 0; r < 4; ++r) {
      const int h = quad * 4 + r;
      xout[(size_t)h * 128 * 1024 + d] = f2bf(xacc[c][r]);
    }
  }
}

// ---------------------------------------------------------------------------
extern "C" void kernel_launch(void* const* d_in, const int* in_sizes, int n_in,
                              void* d_out, int out_size, void* d_ws, size_t ws_size,
                              hipStream_t stream) {
  const float* query = (const float*)d_in[0];
  const float* key = (const float*)d_in[1];
  const float* value = (const float*)d_in[2];
  // d_in[3]=xpos, d_in[4]=ypos unused (rope is None)
  const float* Wq = (const float*)d_in[5];
  const float* Wk = (const float*)d_in[6];
  const float* Wv = (const float*)d_in[7];
  const float* Wp = (const float*)d_in[8];
  const float* bp = (const float*)d_in[9];
  float* out = (float*)d_out;

  const int C = 1024;
  const int M = 8 * 2048;  // 16384 tokens
  const size_t MC = (size_t)M * C;
  const size_t CC = (size_t)C * C;

  // workspace layout (bf16 = uint16), 200 MiB total:
  //   qb,kb,vb,x2b (4x32 MiB), wqb..wpb (4x2 MiB), kin,vin (2x32 MiB)
  //   qin ALIASES x2b (x2b dead until attn; qin dead after QKV GEMM).
  uint16_t* ws = (uint16_t*)d_ws;
  uint16_t* qb = ws;
  uint16_t* kb = qb + MC;
  uint16_t* vb = kb + MC;
  uint16_t* x2b = vb + MC;
  uint16_t* wqb = x2b + MC;
  uint16_t* wkb = wqb + CC;
  uint16_t* wvb = wkb + CC;
  uint16_t* wpb = wvb + CC;
  uint16_t* kin = wpb + CC;
  uint16_t* vin = kin + MC;
  uint16_t* qin = x2b;  // alias (see above)

  // convert q/k/v inputs + all 4 weights to bf16 in one launch
  cvt_all_kernel<<<dim3(26624), dim3(256), 0, stream>>>(
      query, key, value, Wq, Wk, Wv, Wp, qin, kin, vin, wqb, wkb, wvb, wpb);

  // batched QKV projections: 256x256 tiles, grid = 64 m * 4 n * 3 = 768
  GemmBatch qkv;
  qkv.A[0] = qin;  qkv.B[0] = wqb;  qkv.C[0] = qb;
  qkv.A[1] = kin;  qkv.B[1] = wkb;  qkv.C[1] = kb;
  qkv.A[2] = vin;  qkv.B[2] = wvb;  qkv.C[2] = vb;
  gemm8p<true><<<dim3((M / 256) * (C / 256) * 3), dim3(512), 0, stream>>>(qkv, nullptr,
                                                                          M, C, C);

  attn_kernel<<<dim3(M / 4), dim3(256), 0, stream>>>(qb, kb, vb, x2b);

  GemmBatch fin;
  fin.A[0] = x2b;  fin.B[0] = wpb;  fin.C[0] = out;
  fin.A[1] = x2b;  fin.B[1] = wpb;  fin.C[1] = out;
  fin.A[2] = x2b;  fin.B[2] = wpb;  fin.C[2] = out;
  gemm8p<false><<<dim3((M / 256) * (C / 256)), dim3(512), 0, stream>>>(fin, bp, M, C, C);
}